// Round 1
// baseline (325.358 us; speedup 1.0000x reference)
//
#include <hip/hip_runtime.h>
#include <math.h>

#define MASK_THR 0.53f

// Stage 1: priority scatter. packed = (bits(p)<<32) | (0xFFFFFFFF - idx)
// atomicMax => winner = max prob, tie -> min idx. Matches lexsort(key asc, -p, idx).
__global__ void k_scatter(const float* __restrict__ prob,
                          const int* __restrict__ coords,  // [2, NE] flat
                          unsigned long long* __restrict__ packed,
                          int NE, const int* __restrict__ d_size1) {
    int i = blockIdx.x * blockDim.x + threadIdx.x;
    if (i >= NE) return;
    float p = prob[i];
    if (p >= MASK_THR) {
        int size1 = *d_size1;
        int x = coords[i];
        int y = coords[NE + i];
        int key = x * size1 + y;
        unsigned long long v =
            ((unsigned long long)__float_as_uint(p) << 32) |
            (unsigned long long)(0xFFFFFFFFu - (unsigned)i);
        atomicMax(&packed[key], v);
    }
}

// Stage 2a: M = A + I
__global__ void k_build_M(const float* __restrict__ adj, float* __restrict__ M, int N) {
    int i = blockIdx.x * blockDim.x + threadIdx.x;
    if (i >= N * N) return;
    int r = i / N, c = i - r * N;
    M[i] = adj[i] + (r == c ? 1.0f : 0.0f);
}

// Stage 2b: simple LDS-tiled fp32 matmul, N divisible by 16.
#define TS 16
__global__ void k_matmul(const float* __restrict__ A, const float* __restrict__ B,
                         float* __restrict__ C, int N) {
    __shared__ float As[TS][TS];
    __shared__ float Bs[TS][TS + 1];
    int row = blockIdx.y * TS + threadIdx.y;
    int col = blockIdx.x * TS + threadIdx.x;
    float acc = 0.0f;
    for (int t = 0; t < N; t += TS) {
        As[threadIdx.y][threadIdx.x] = A[row * N + t + threadIdx.x];
        Bs[threadIdx.y][threadIdx.x] = B[(t + threadIdx.y) * N + col];
        __syncthreads();
#pragma unroll
        for (int k = 0; k < TS; ++k)
            acc += As[threadIdx.y][k] * Bs[k][threadIdx.x];
        __syncthreads();
    }
    C[row * N + col] = acc;
}

// Stage 2c: remap[j] = 1 + max({j} U {i != j : P10[i][j] > 1})
__global__ void k_remap(const float* __restrict__ P10, float* __restrict__ remap, int N) {
    int j = blockIdx.x * blockDim.x + threadIdx.x;
    if (j >= N) return;
    int best = j;
    for (int i = 0; i < N; ++i) {
        if (i != j && P10[(long)i * N + j] > 1.0f && i > best) best = i;
    }
    remap[j] = (float)(best + 1);
}

// Stage 3: gather remap through the winning label.
__global__ void k_finalize(const unsigned long long* __restrict__ packed,
                           const float* __restrict__ remap,
                           float* __restrict__ out, int total, int HW) {
    int i = blockIdx.x * blockDim.x + threadIdx.x;
    if (i >= total) return;
    unsigned long long v = packed[i];
    float o = 0.0f;
    if (v != 0ull) {
        unsigned idx = 0xFFFFFFFFu - (unsigned)(v & 0xFFFFFFFFull);
        int n = (int)(idx / (unsigned)HW);
        o = remap[n];
    }
    out[i] = o;
}

extern "C" void kernel_launch(void* const* d_in, const int* in_sizes, int n_in,
                              void* d_out, int out_size, void* d_ws, size_t ws_size,
                              hipStream_t stream) {
    const float* prob   = (const float*)d_in[0];
    const int*   coords = (const int*)d_in[1];
    const float* adj    = (const float*)d_in[2];
    const int*   dsz1   = (const int*)d_in[4];

    const int NE = in_sizes[0];            // N*h*w = 4718592
    const int NN = in_sizes[2];            // N*N
    const int N  = (int)(sqrt((double)NN) + 0.5);   // 512
    const int HW = NE / N;                 // 9216
    const int total = out_size;            // size0*size1 = 1048576

    char* ws = (char*)d_ws;
    unsigned long long* packed = (unsigned long long*)ws;
    size_t off = (size_t)total * 8;
    float* b0 = (float*)(ws + off); off += (size_t)NN * 4;
    float* b1 = (float*)(ws + off); off += (size_t)NN * 4;
    float* b2 = (float*)(ws + off); off += (size_t)NN * 4;
    float* remap = (float*)(ws + off);

    hipMemsetAsync(packed, 0, (size_t)total * 8, stream);

    k_scatter<<<(NE + 255) / 256, 256, 0, stream>>>(prob, coords, packed, NE, dsz1);

    k_build_M<<<(NN + 255) / 256, 256, 0, stream>>>(adj, b0, N);
    dim3 mb(TS, TS), mg(N / TS, N / TS);
    k_matmul<<<mg, mb, 0, stream>>>(b0, b0, b1, N);  // M^2
    k_matmul<<<mg, mb, 0, stream>>>(b1, b1, b0, N);  // M^4
    k_matmul<<<mg, mb, 0, stream>>>(b0, b0, b2, N);  // M^8
    k_matmul<<<mg, mb, 0, stream>>>(b2, b1, b0, N);  // M^10 = M^8 * M^2

    k_remap<<<(N + 255) / 256, 256, 0, stream>>>(b0, remap, N);

    k_finalize<<<(total + 255) / 256, 256, 0, stream>>>(packed, remap, (float*)d_out, total, HW);
}

// Round 2
// 177.122 us; speedup vs baseline: 1.8369x; 1.8369x over previous
//
#include <hip/hip_runtime.h>
#include <math.h>

#define MASK_THR 0.53f

// Stage 1: priority scatter. packed = (bits(p)<<32) | (0xFFFFFFFF - idx)
// atomicMax => winner = max prob, tie -> min idx. Matches lexsort(key asc, -p, idx).
// Vectorized: each thread handles 4 consecutive pixels (float4 / int4 loads).
__global__ void k_scatter(const float* __restrict__ prob,
                          const int* __restrict__ coords,  // [2, NE] flat
                          unsigned long long* __restrict__ packed,
                          int NE, const int* __restrict__ d_size1) {
    int i4 = blockIdx.x * blockDim.x + threadIdx.x;
    int base = i4 * 4;
    if (base >= NE) return;
    int size1 = *d_size1;
    float4 p = ((const float4*)prob)[i4];
    int4 x = ((const int4*)coords)[i4];
    int4 y = ((const int4*)(coords + NE))[i4];
    float pv[4] = {p.x, p.y, p.z, p.w};
    int   xv[4] = {x.x, x.y, x.z, x.w};
    int   yv[4] = {y.x, y.y, y.z, y.w};
#pragma unroll
    for (int e = 0; e < 4; ++e) {
        if (pv[e] >= MASK_THR) {
            int key = xv[e] * size1 + yv[e];
            unsigned long long v =
                ((unsigned long long)__float_as_uint(pv[e]) << 32) |
                (unsigned long long)(0xFFFFFFFFu - (unsigned)(base + e));
            atomicMax(&packed[key], v);
        }
    }
}

// Stage 2a: M = A + I
__global__ void k_build_M(const float* __restrict__ adj, float* __restrict__ M, int N) {
    int i = blockIdx.x * blockDim.x + threadIdx.x;
    if (i >= N * N) return;
    int r = i / N, c = i - r * N;
    M[i] = adj[i] + (r == c ? 1.0f : 0.0f);
}

// Stage 2b: 32x32-tile fp32 matmul, 2x2 register blocking, N % 32 == 0.
#define BT 32
__global__ __launch_bounds__(256) void k_matmul(const float* __restrict__ A,
                                                const float* __restrict__ B,
                                                float* __restrict__ C, int N) {
    __shared__ float As[BT][BT + 1];
    __shared__ float Bs[BT][BT + 1];
    int tid = threadIdx.x;           // 0..255
    int tx = tid & 15, ty = tid >> 4; // 16x16 compute layout, 2x2 each
    int rowBase = blockIdx.y * BT;
    int colBase = blockIdx.x * BT;
    int lr = tid >> 3;               // load row 0..31
    int lc = (tid & 7) * 4;          // load col 0,4,..,28
    float a00 = 0, a01 = 0, a10 = 0, a11 = 0;
    for (int t = 0; t < N; t += BT) {
        float4 av = *(const float4*)&A[(size_t)(rowBase + lr) * N + t + lc];
        float4 bv = *(const float4*)&B[(size_t)(t + lr) * N + colBase + lc];
        As[lr][lc + 0] = av.x; As[lr][lc + 1] = av.y;
        As[lr][lc + 2] = av.z; As[lr][lc + 3] = av.w;
        Bs[lr][lc + 0] = bv.x; Bs[lr][lc + 1] = bv.y;
        Bs[lr][lc + 2] = bv.z; Bs[lr][lc + 3] = bv.w;
        __syncthreads();
#pragma unroll
        for (int k = 0; k < BT; ++k) {
            float a0 = As[ty * 2][k], a1 = As[ty * 2 + 1][k];
            float b0 = Bs[k][tx * 2], b1 = Bs[k][tx * 2 + 1];
            a00 += a0 * b0; a01 += a0 * b1;
            a10 += a1 * b0; a11 += a1 * b1;
        }
        __syncthreads();
    }
    int r0 = rowBase + ty * 2, c0 = colBase + tx * 2;
    C[(size_t)r0 * N + c0] = a00;
    C[(size_t)r0 * N + c0 + 1] = a01;
    C[(size_t)(r0 + 1) * N + c0] = a10;
    C[(size_t)(r0 + 1) * N + c0 + 1] = a11;
}

// Stage 2c: remap[j] = 1 + max({j} U {i != j : cls(i,j)}).
// cls is symmetric (symmetric adjacency => symmetric walk counts; the >1
// classification is exact under fp32: true 0/1 entries are computed exactly,
// true >=2 entries keep >1 under relative rounding). So read ROW j (coalesced).
// One wave per j, shuffle-reduce the max.
__global__ void k_remap(const float* __restrict__ P10, float* __restrict__ remap, int N) {
    int j = blockIdx.x;
    int lane = threadIdx.x;  // 64
    const float* row = P10 + (size_t)j * N;
    int best = j;
    for (int i = lane; i < N; i += 64) {
        if (i != j && row[i] > 1.0f && i > best) best = i;
    }
    for (int off = 32; off; off >>= 1) {
        int o = __shfl_down(best, off);
        if (o > best) best = o;
    }
    if (lane == 0) remap[j] = (float)(best + 1);
}

// Stage 3: gather remap through the winning label.
__global__ void k_finalize(const unsigned long long* __restrict__ packed,
                           const float* __restrict__ remap,
                           float* __restrict__ out, int total, int HW) {
    int i = blockIdx.x * blockDim.x + threadIdx.x;
    if (i >= total) return;
    unsigned long long v = packed[i];
    float o = 0.0f;
    if (v != 0ull) {
        unsigned idx = 0xFFFFFFFFu - (unsigned)(v & 0xFFFFFFFFull);
        int n = (int)(idx / (unsigned)HW);
        o = remap[n];
    }
    out[i] = o;
}

extern "C" void kernel_launch(void* const* d_in, const int* in_sizes, int n_in,
                              void* d_out, int out_size, void* d_ws, size_t ws_size,
                              hipStream_t stream) {
    const float* prob   = (const float*)d_in[0];
    const int*   coords = (const int*)d_in[1];
    const float* adj    = (const float*)d_in[2];
    const int*   dsz1   = (const int*)d_in[4];

    const int NE = in_sizes[0];            // N*h*w = 4718592
    const int NN = in_sizes[2];            // N*N
    const int N  = (int)(sqrt((double)NN) + 0.5);   // 512
    const int HW = NE / N;                 // 9216
    const int total = out_size;            // size0*size1 = 1048576

    char* ws = (char*)d_ws;
    unsigned long long* packed = (unsigned long long*)ws;
    size_t off = (size_t)total * 8;
    float* b0 = (float*)(ws + off); off += (size_t)NN * 4;
    float* b1 = (float*)(ws + off); off += (size_t)NN * 4;
    float* b2 = (float*)(ws + off); off += (size_t)NN * 4;
    float* remap = (float*)(ws + off);

    hipMemsetAsync(packed, 0, (size_t)total * 8, stream);

    k_scatter<<<(NE / 4 + 255) / 256, 256, 0, stream>>>(prob, coords, packed, NE, dsz1);

    k_build_M<<<(NN + 255) / 256, 256, 0, stream>>>(adj, b0, N);
    dim3 mg(N / BT, N / BT);
    k_matmul<<<mg, 256, 0, stream>>>(b0, b0, b1, N);  // M^2
    k_matmul<<<mg, 256, 0, stream>>>(b1, b1, b0, N);  // M^4
    k_matmul<<<mg, 256, 0, stream>>>(b0, b0, b2, N);  // M^8
    k_matmul<<<mg, 256, 0, stream>>>(b2, b1, b0, N);  // M^10 = M^8 * M^2

    k_remap<<<N, 64, 0, stream>>>(b0, remap, N);

    k_finalize<<<(total + 255) / 256, 256, 0, stream>>>(packed, remap, (float*)d_out, total, HW);
}